// Round 6
// baseline (105.392 us; speedup 1.0000x reference)
//
#include <hip/hip_runtime.h>
#include <math.h>

// ---------------------------------------------------------------------------
// CategoricalAwareTabularEncoder — design 7 (fragment-order LDS, PART/2)
//
// Key algebra (unchanged): pair-MLP layer-1 factorizes:
//   pairs(i,j)@W1 = emb_i@W1a + emb_j@W1b
//   U = emb@W1a + b1, V = emb@W1b, Hsum[d] = sum_{i<j} relu(U_i[d]+V_j[d]),
//   combo_sum = Hsum@W2 + P*b2.
//
// Design-7 changes vs design-6:
//  * MFMA operands pre-packed in EXACT fragment order:
//      WB[mat][kk][tc][lane] h8  (B-frags)  — 1536 elems, 24.6 KB
//      EA[kk][tr][lane]      h8  (A-frags)  —  512 elems,  8 KB
//    Every fragment read is ONE lane-consecutive ds_read_b128 (conflict-free):
//    interval-1 reads 216 -> 120, conflicts -> 0.  Same math, same slot map
//    as design 6 (HW-validated): elem holds k = kk*32+8*grp..+7 for
//    column/row tc*16+col.
//  * Phase B merges the two g-halves of each wave in-register
//    (__shfl_xor lane^32 + f32 add): PART 32 rows -> 16; tail reads halve.
//  * Cluster waves read E row-fragments from EA (8 b128/lane-token).
// ---------------------------------------------------------------------------

typedef _Float16 h2 __attribute__((ext_vector_type(2)));
typedef _Float16 h4 __attribute__((ext_vector_type(4)));
typedef _Float16 h8 __attribute__((ext_vector_type(8)));
typedef float    f4 __attribute__((ext_vector_type(4)));
union H4u { h4 v; h2 h[2]; };
union H8u { h8 v; h2 h[4]; };

constexpr int BATCH = 256;
constexpr int S = 64, D = 64, F = 10;
constexpr int NPAIR = S * (S - 1) / 2;  // 2016

// LDS map in 4-byte units (total 15616 u32 = 62464 B < 64 KB)
constexpr int WB_F = 0;      // 1536 h8 B-frag elems (6144 u32); dead after int1
constexpr int EA_F = 6144;   // 512 h8 A-frag elems (2048 u32)
constexpr int U2B  = 8192;   // [s][d2] h2, stride 32 (2048)
constexpr int V2T  = 10240;  // [d2][j] h2, stride 66 (2112)
constexpr int FHT  = 12352;  // [s][d2] h2, stride 34 (2176)
constexpr int DI_F = 14528;  // f32 [64][stride 11] raw distances (704)
constexpr int W2P  = 15232;  // [f*32+d2] h2 packed freq_w2 (320)
constexpr int FRQ  = 15552;  // f32 [64] cat_freq/total_samples (64)
constexpr int PART_F = 0;    // f32 [16 w][64 d] (1024), aliases dead WB

__device__ __forceinline__ h2 pk2(float a, float b) {
#if __has_builtin(__builtin_amdgcn_cvt_pkrtz)
  auto t = __builtin_amdgcn_cvt_pkrtz(a, b);
  return __builtin_bit_cast(h2, t);
#else
  h2 r; r.x = (_Float16)a; r.y = (_Float16)b; return r;
#endif
}

__device__ __forceinline__ float fdot2f(h2 a, h2 b, float c) {
#if __has_builtin(__builtin_amdgcn_fdot2)
  typedef __fp16 q2 __attribute__((ext_vector_type(2)));
  return __builtin_amdgcn_fdot2(__builtin_bit_cast(q2, a),
                                __builtin_bit_cast(q2, b), c, false);
#else
  return c + (float)a.x * (float)b.x + (float)a.y * (float)b.y;
#endif
}

__device__ __forceinline__ h2 hmax2z(h2 a) {  // elementwise max(a, 0)
#if __has_builtin(__builtin_elementwise_max)
  h2 z = {(_Float16)0, (_Float16)0};
  return __builtin_elementwise_max(a, z);
#else
  h2 r;
  r.x = a.x > (_Float16)0 ? a.x : (_Float16)0;
  r.y = a.y > (_Float16)0 ? a.y : (_Float16)0;
  return r;
#endif
}

// value of lane (l+1) for even lanes l, via quad_perm [1,1,3,3]
__device__ __forceinline__ float lane_up1(float v) {
#if __has_builtin(__builtin_amdgcn_update_dpp)
  int r = __builtin_amdgcn_update_dpp(0, __float_as_int(v), 0xF5, 0xF, 0xF, false);
  return __int_as_float(r);
#else
  return __shfl_down(v, 1, 64);
#endif
}

__global__ __launch_bounds__(1024, 4)
void cat_enc_kernel(const int*   __restrict__ ids,
                    const float* __restrict__ emb_table,
                    const float* __restrict__ comb_w1,
                    const float* __restrict__ comb_b1,
                    const float* __restrict__ comb_w2,
                    const float* __restrict__ comb_b2,
                    const float* __restrict__ freq_w1,
                    const float* __restrict__ freq_b1,
                    const float* __restrict__ freq_w2,
                    const float* __restrict__ freq_b2,
                    const float* __restrict__ centers,
                    const float* __restrict__ cat_freq,
                    const float* __restrict__ total_samples,
                    float*       __restrict__ out)
{
  __shared__ __align__(16) unsigned int ldsu[15616];
  h2*    ldsH = (h2*)ldsu;
  float* ldsf = (float*)ldsu;
  const int tid = threadIdx.x;
  const int b = blockIdx.x, bBase = b * S;
  float ffreg = 0.f;   // freq_feat[s=lane][f=wave] register (waves 0-9)

  // ---------------- stage: gather emb + freqs + pack fragments --------------
  {
    // emb gather first: dependent-load chain (ids -> row), start it early
    const int s = tid >> 4, q = tid & 15;
    const int id = ids[bBase + s];
    float4 e4 = *(const float4*)(emb_table + (size_t)id * D + q * 4);
    H4u ep; ep.h[0] = pk2(e4.x, e4.y); ep.h[1] = pk2(e4.z, e4.w);
    // EA: elem (kk*4+tr)*64 + col + 16*grp holds E[s][kk*32+8*grp .. +7]
    {
      const int kk = q >> 3, grp = (q & 7) >> 1;
      const int elem = (kk * 4 + (s >> 4)) * 64 + (s & 15) + 16 * grp;
      *(h4*)&ldsH[EA_F + elem * 4 + (q & 1) * 2] = ep.v;   // b64 write
    }
    if (q == 0) ldsf[FRQ + s] = cat_freq[id] * (1.0f / total_samples[0]);

    // WB pack: elem e = ((mat*2+kk)*4+tc)*64 + lane holds
    //          Wmat[k = kk*32 + (lane>>4)*8 .. +7][tc*16 + (lane&15)]
#pragma unroll
    for (int it = 0; it < 2; ++it) {
      if (it == 1 && tid >= 512) break;
      const int e = tid + it * 1024;
      const int lane_e = e & 63, tc = (e >> 6) & 3, kk = (e >> 8) & 1, mat = e >> 9;
      const int brow = tc * 16 + (lane_e & 15);
      const int kbase = kk * 32 + (lane_e >> 4) * 8;
      const float* src = ((mat == 0) ? comb_w1
                        : (mat == 1) ? comb_w1 + D * D
                                     : freq_w1) + kbase * D + brow;
      H8u w;
      w.h[0] = pk2(src[0],     src[D]);
      w.h[1] = pk2(src[2 * D], src[3 * D]);
      w.h[2] = pk2(src[4 * D], src[5 * D]);
      w.h[3] = pk2(src[6 * D], src[7 * D]);
      *(h8*)&ldsH[WB_F + e * 4] = w.v;   // lane-consecutive b128, conflict-free
    }
    if (tid < 320) {
      int f = tid >> 5, d2 = tid & 31;
      ldsH[W2P + tid] = pk2(freq_w2[(2 * d2) * F + f], freq_w2[(2 * d2 + 1) * F + f]);
    }
  }
  __syncthreads();

  // ------- interval 1: MFMA phase A (waves 0-11) || cluster (waves 12-15) ---
  {
    const int wv   = __builtin_amdgcn_readfirstlane((int)(tid >> 6));
    const int lane = tid & 63;
    if (wv < 12) {
      const int mat = wv >> 2, tr = wv & 3;
      const int col = lane & 15, grp = lane >> 4;
      const int base = tr * 16 + grp * 4;     // C/D row base (token)
      // A-frags: one conflict-free b128 each
      h8 A0 = *(const h8*)&ldsH[EA_F + (tr * 64 + lane) * 4];        // k 0..31
      h8 A1 = *(const h8*)&ldsH[EA_F + ((4 + tr) * 64 + lane) * 4];  // k 32..63
      f4 acc[4];
#pragma unroll
      for (int tc = 0; tc < 4; ++tc) {
        h8 B0 = *(const h8*)&ldsH[WB_F + (((mat * 2 + 0) * 4 + tc) * 64 + lane) * 4];
        h8 B1 = *(const h8*)&ldsH[WB_F + (((mat * 2 + 1) * 4 + tc) * 64 + lane) * 4];
        f4 c = {0.f, 0.f, 0.f, 0.f};
        c = __builtin_amdgcn_mfma_f32_16x16x32_f16(A0, B0, c, 0, 0, 0);
        c = __builtin_amdgcn_mfma_f32_16x16x32_f16(A1, B1, c, 0, 0, 0);
        acc[tc] = c;
      }
      const bool evenc = ((col & 1) == 0);
      if (mat == 0) {                         // U = E@W1a + b1 -> U2B [s][d2]
#pragma unroll
        for (int tc = 0; tc < 4; ++tc) {
          const float bv = comb_b1[tc * 16 + col];
          float v0 = acc[tc][0] + bv, v1 = acc[tc][1] + bv,
                v2 = acc[tc][2] + bv, v3 = acc[tc][3] + bv;
          float n0 = lane_up1(v0), n1 = lane_up1(v1),
                n2 = lane_up1(v2), n3 = lane_up1(v3);
          if (evenc) {
            const int d2 = tc * 8 + (col >> 1);
            ldsH[U2B + (base + 0) * 32 + d2] = pk2(v0, n0);
            ldsH[U2B + (base + 1) * 32 + d2] = pk2(v1, n1);
            ldsH[U2B + (base + 2) * 32 + d2] = pk2(v2, n2);
            ldsH[U2B + (base + 3) * 32 + d2] = pk2(v3, n3);
          }
        }
      } else if (mat == 1) {                  // V = E@W1b -> V2T [d2][j]
#pragma unroll
        for (int tc = 0; tc < 4; ++tc) {
          float v0 = acc[tc][0], v1 = acc[tc][1],
                v2 = acc[tc][2], v3 = acc[tc][3];
          float n0 = lane_up1(v0), n1 = lane_up1(v1),
                n2 = lane_up1(v2), n3 = lane_up1(v3);
          if (evenc) {
            const int d2 = tc * 8 + (col >> 1);
            H4u w01; w01.h[0] = pk2(v0, n0); w01.h[1] = pk2(v1, n1);
            *(h4*)&ldsH[V2T + d2 * 66 + base] = w01.v;       // rows j..j+1
            H4u w23; w23.h[0] = pk2(v2, n2); w23.h[1] = pk2(v3, n3);
            *(h4*)&ldsH[V2T + d2 * 66 + base + 2] = w23.v;   // rows j+2..j+3
          }
        }
      } else {                                // FH = relu(E@Wf + frq*wL + fb1)
        const f4 frq4 = *(const f4*)&ldsf[FRQ + base];
#pragma unroll
        for (int tc = 0; tc < 4; ++tc) {
          const int d = tc * 16 + col;
          const float fwv = freq_w1[D * D + d], fbv = freq_b1[d];
          float v0 = fmaxf(fmaf(frq4[0], fwv, acc[tc][0]) + fbv, 0.f);
          float v1 = fmaxf(fmaf(frq4[1], fwv, acc[tc][1]) + fbv, 0.f);
          float v2 = fmaxf(fmaf(frq4[2], fwv, acc[tc][2]) + fbv, 0.f);
          float v3 = fmaxf(fmaf(frq4[3], fwv, acc[tc][3]) + fbv, 0.f);
          float n0 = lane_up1(v0), n1 = lane_up1(v1),
                n2 = lane_up1(v2), n3 = lane_up1(v3);
          if (evenc) {
            const int d2 = tc * 8 + (col >> 1);
            ldsH[FHT + (base + 0) * 34 + d2] = pk2(v0, n0);
            ldsH[FHT + (base + 1) * 34 + d2] = pk2(v1, n1);
            ldsH[FHT + (base + 2) * 34 + d2] = pk2(v2, n2);
            ldsH[FHT + (base + 3) * 34 + d2] = pk2(v3, n3);
          }
        }
      }
    } else {
      // ---- cluster distances: lane = token s; waves 12-15, centers cc ----
      const int s = lane, trs = s >> 4, cols = s & 15;
      H8u er[2][4];
#pragma unroll
      for (int kk = 0; kk < 2; ++kk)
#pragma unroll
        for (int g = 0; g < 4; ++g)
          er[kk][g].v = *(const h8*)&ldsH[EA_F + ((kk * 4 + trs) * 64 + cols + 16 * g) * 4];
      for (int cc = wv - 12; cc < 10; cc += 4) {
        const float* crow = centers + cc * D;  // uniform -> s_load
        float acc = 0.f;
#pragma unroll
        for (int kk = 0; kk < 2; ++kk)
#pragma unroll
          for (int g = 0; g < 4; ++g)
#pragma unroll
            for (int t = 0; t < 4; ++t) {
              const int k2 = kk * 16 + g * 4 + t;
              float t0 = (float)er[kk][g].h[t].x - crow[2 * k2];
              float t1 = (float)er[kk][g].h[t].y - crow[2 * k2 + 1];
              acc = fmaf(t0, t0, fmaf(t1, t1, acc));
            }
        ldsf[DI_F + s * 11 + cc] = sqrtf(acc);   // stride 11: conflict-free
      }
    }
  }
  __syncthreads();

  // ------- interval 2: freq_feat into regs (waves 0-9) then phase B (all) ---
  {
    if (tid < 640) {
      int s = tid & 63;
      int f = __builtin_amdgcn_readfirstlane((int)(tid >> 6));  // wave = f
      float acc = freq_b2[f];
      const h8* wrow = (const h8*)&ldsH[W2P + f * 32];
#pragma unroll
      for (int d8 = 0; d8 < 4; ++d8) {
        H8u wf; wf.v = wrow[d8];                                  // b128 bcast
        H4u f0; f0.v = *(const h4*)&ldsH[FHT + s * 34 + d8 * 4];      // b64
        H4u f1; f1.v = *(const h4*)&ldsH[FHT + s * 34 + d8 * 4 + 2];  // b64
        acc = fdot2f(f0.h[0], wf.h[0], acc);
        acc = fdot2f(f0.h[1], wf.h[1], acc);
        acc = fdot2f(f1.h[0], wf.h[2], acc);
        acc = fdot2f(f1.h[1], wf.h[3], acc);
      }
      ffreg = acc;                       // stays in a register
    }
  }

  // ------- phase B: Hsum partials, group g owns rows {g, 63-g} --------------
  {
    const int dg = tid & 31, g = tid >> 5;
    h2 u2a = ldsH[U2B + g * 32 + dg];
    h2 u2b = ldsH[U2B + (63 - g) * 32 + dg];
    h2 za = {(_Float16)0, (_Float16)0};
    h2 acA0 = za, acA1 = za, accb = za;
    const int jsplit = 64 - g;      // row-b active for j >= jsplit (never in head)
    int j = g + 1;
    if (j & 1) {                    // scalar head to even j
      h2 v2 = ldsH[V2T + dg * 66 + j];
      acA0 = acA0 + hmax2z(u2a + v2);
      ++j;
    }
#pragma unroll 4
    for (; j < 64; j += 2) {
      H4u v; v.v = *(const h4*)&ldsH[V2T + dg * 66 + j];   // b64: j, j+1
      acA0 = acA0 + hmax2z(u2a + v.h[0]);
      acA1 = acA1 + hmax2z(u2a + v.h[1]);
      if (j + 1 >= jsplit) {
        if (j >= jsplit) accb = accb + hmax2z(u2b + v.h[0]);
        accb = accb + hmax2z(u2b + v.h[1]);
      }
    }
    h2 at = acA0 + acA1 + accb;
    // merge the two g-halves of this wave (lane^32 shares dg): PART 32 -> 16
    float ax = (float)at.x, ay = (float)at.y;
    ax += __shfl_xor(ax, 32, 64);
    ay += __shfl_xor(ay, 32, 64);
    if ((tid & 63) < 32) {
      const int w = tid >> 6;
      float2 wr = {ax, ay};
      *(float2*)&ldsf[PART_F + w * 64 + 2 * dg] = wr;   // b64 write
    }
  }
  __syncthreads();

  // ------- fused tail (waves 0-9): reduce+combo_sum, softmax, store ---------
  if (tid < 640) {
    const int f = __builtin_amdgcn_readfirstlane((int)(tid >> 6));
    const int l = tid & 63;
    // (1) Hsum reduce along l=d (16 merged rows), butterfly to CS[f]
    float h = 0.f;
#pragma unroll
    for (int w = 0; w < 16; ++w) h += ldsf[PART_F + w * 64 + l];
    float p = h * comb_w2[l * F + f];
#pragma unroll
    for (int off = 1; off < 64; off <<= 1) p += __shfl_xor(p, off, 64);
    const float cs = fmaf(comb_b2[f], (float)NPAIR, p);
    // (2) per-lane softmax over the 10 raw distances for token s=l
    float dv[10], dmin = 1e30f;
#pragma unroll
    for (int c = 0; c < 10; ++c) { dv[c] = ldsf[DI_F + l * 11 + c]; dmin = fminf(dmin, dv[c]); }
    float sum = 0.f;
#pragma unroll
    for (int c = 0; c < 10; ++c) sum += expf(dmin - dv[c]);
    const float clu = expf(dmin - dv[f]) / sum;
    const float val = (ffreg + cs + clu) * (1.0f / (float)(NPAIR + 2));
    out[(size_t)b * 640 + l * 10 + f] = val;
  }
}

extern "C" void kernel_launch(void* const* d_in, const int* in_sizes, int n_in,
                              void* d_out, int out_size, void* d_ws, size_t ws_size,
                              hipStream_t stream) {
  (void)in_sizes; (void)n_in; (void)d_ws; (void)ws_size; (void)out_size;
  const int*   ids        = (const int*)  d_in[0];
  const float* emb_table  = (const float*)d_in[1];
  const float* comb_w1    = (const float*)d_in[2];
  const float* comb_b1    = (const float*)d_in[3];
  const float* comb_w2    = (const float*)d_in[4];
  const float* comb_b2    = (const float*)d_in[5];
  const float* freq_w1    = (const float*)d_in[6];
  const float* freq_b1    = (const float*)d_in[7];
  const float* freq_w2    = (const float*)d_in[8];
  const float* freq_b2    = (const float*)d_in[9];
  const float* centers    = (const float*)d_in[10];
  const float* cat_freq   = (const float*)d_in[11];
  const float* total_samp = (const float*)d_in[12];
  float* out = (float*)d_out;

  hipLaunchKernelGGL(cat_enc_kernel, dim3(BATCH), dim3(1024), 0, stream,
                     ids, emb_table, comb_w1, comb_b1, comb_w2, comb_b2,
                     freq_w1, freq_b1, freq_w2, freq_b2, centers, cat_freq,
                     total_samp, out);
}